// Round 1
// baseline (264.487 us; speedup 1.0000x reference)
//
#include <hip/hip_runtime.h>
#include <hip/hip_bf16.h>
#include <stdint.h>

// Problem dims
#define NB 256
#define NL 196
#define NE 2048
#define ND 512
#define NA 512
#define NM (NB * NL)  // 50176

typedef __attribute__((ext_vector_type(4))) float f32x4;
typedef __attribute__((ext_vector_type(8))) short bf16x8;

static __device__ __forceinline__ unsigned short f2bf(float f) {
  union { float f; uint32_t u; } c; c.f = f;
  uint32_t u = c.u;
  return (unsigned short)((u + 0x7fffu + ((u >> 16) & 1u)) >> 16);  // RNE
}

// ---------------- kernel 0: pack W_enc (fp32 [2048][512]) into B-fragment order bf16
// Bpack[ntile(32)][kt32(64)][lane(64)][j(8)] = W_enc[kt32*32 + (lane>>4)*8 + j][ntile*16 + (lane&15)]
__global__ void k_pack_b(const float* __restrict__ W, unsigned short* __restrict__ Bp) {
  int t = blockIdx.x * 256 + threadIdx.x;  // 0..131071
  int lane = t & 63;
  int kt32 = (t >> 6) & 63;
  int ntile = t >> 12;  // 0..31
  int col = ntile * 16 + (lane & 15);
  int k0 = kt32 * 32 + ((lane >> 4) << 3);
  bf16x8 o;
#pragma unroll
  for (int j = 0; j < 8; ++j) o[j] = (short)f2bf(W[(size_t)(k0 + j) * NA + col]);
  *reinterpret_cast<bf16x8*>(Bp + ((size_t)t << 3)) = o;
}

// ---------------- kernel 1: d2[b][a] = dec[b]·W_dec[:,a] + b_dec[a] + b_enc[a]
__global__ void k_dec(const float* __restrict__ dec, const float* __restrict__ Wd,
                      const float* __restrict__ bd, const float* __restrict__ be,
                      float* __restrict__ d2) {
  __shared__ float dh[ND];
  int b = blockIdx.x, tid = threadIdx.x;  // 512 threads
  dh[tid] = dec[(size_t)b * ND + tid];
  __syncthreads();
  float s = bd[tid] + be[tid];
#pragma unroll 8
  for (int e = 0; e < ND; ++e) s = fmaf(dh[e], Wd[(size_t)e * NA + tid], s);
  d2[(size_t)b * NA + tid] = s;
}

// ---------------- kernel 2: main fused GEMM + relu-dot epilogue
// att[row] = sum_a relu( (enc@W_enc)[row][a] + d2[b(row)][a] ) * W_att[a] + b_att
#define BM 64
#define BK 64
#define KT (NE / BK)  // 32

__global__ __launch_bounds__(512, 4) void k_main(
    const float* __restrict__ A,            // [NM][NE] fp32
    const unsigned short* __restrict__ Bp,  // packed bf16 B
    const float* __restrict__ d2,           // [NB][NA]
    const float* __restrict__ Watt,         // [NA]
    const float* __restrict__ batt,         // [1]
    float* __restrict__ att)                // [NM]
{
  __shared__ unsigned short As[2][BM * BK];  // 8 KB each, XOR-swizzled rows
  __shared__ float att_w[8][BM];

  const int tid = threadIdx.x;
  const int lane = tid & 63;
  const int wid = tid >> 6;   // wave 0..7 -> col slice wid*64
  const int lq = lane >> 4;   // 0..3
  const int lr = lane & 15;
  const int row0 = blockIdx.x * BM;

  // acc init with d2 (folds decoder term + both biases into MFMA C-in)
  f32x4 acc[4][4];
#pragma unroll
  for (int mf = 0; mf < 4; ++mf)
#pragma unroll
    for (int r = 0; r < 4; ++r) {
      int rowg = row0 + mf * 16 + lq * 4 + r;
      int bb = rowg / NL;
      const float* d2r = d2 + (size_t)bb * NA + wid * 64 + lr;
#pragma unroll
      for (int nf = 0; nf < 4; ++nf) acc[mf][nf][r] = d2r[nf * 16];
    }

  // A staging map: thread -> (row 0..63, 8-elem k-chunk 0..7)
  const int srow = tid >> 3;
  const int skc = tid & 7;
  const float* ag = A + (size_t)(row0 + srow) * NE + skc * 8;
  const int swz_w = srow * 64 + ((skc ^ (srow & 7)) << 3);  // ushort index, 16B-swizzled

  auto cvt_store = [&](int buf, const f32x4& a, const f32x4& b) {
    bf16x8 o;
    o[0] = (short)f2bf(a[0]); o[1] = (short)f2bf(a[1]);
    o[2] = (short)f2bf(a[2]); o[3] = (short)f2bf(a[3]);
    o[4] = (short)f2bf(b[0]); o[5] = (short)f2bf(b[1]);
    o[6] = (short)f2bf(b[2]); o[7] = (short)f2bf(b[3]);
    *reinterpret_cast<bf16x8*>(&As[buf][swz_w]) = o;
  };

  // prologue: stage kt=0
  {
    f32x4 p0 = *reinterpret_cast<const f32x4*>(ag);
    f32x4 p1 = *reinterpret_cast<const f32x4*>(ag + 4);
    cvt_store(0, p0, p1);
  }
  __syncthreads();

  // per-wave B base: element ((ntile*64 + kt32)*64 + lane)*8, ntile = wid*4+nf
  const unsigned short* bpw = Bp + (size_t)(wid * 4) * 32768 + lane * 8;

  for (int kt = 0; kt < KT; ++kt) {
    const int cur = kt & 1;
    f32x4 n0, n1;
    if (kt < KT - 1) {
      const float* agn = ag + (size_t)(kt + 1) * BK;
      n0 = *reinterpret_cast<const f32x4*>(agn);
      n1 = *reinterpret_cast<const f32x4*>(agn + 4);
    }
    // B fragments for this K-tile (L2-resident, coalesced 1KB/wave each)
    bf16x8 bf[4][2];
#pragma unroll
    for (int nf = 0; nf < 4; ++nf)
#pragma unroll
      for (int ks = 0; ks < 2; ++ks)
        bf[nf][ks] = *reinterpret_cast<const bf16x8*>(bpw + (size_t)nf * 32768 + (kt * 2 + ks) * 512);
    // A fragments from LDS + MFMA
#pragma unroll
    for (int ks = 0; ks < 2; ++ks)
#pragma unroll
      for (int mf = 0; mf < 4; ++mf) {
        const int rrow = mf * 16 + lr;
        const int chunk = (ks * 4 + lq) ^ (lr & 7);
        bf16x8 af = *reinterpret_cast<const bf16x8*>(&As[cur][rrow * 64 + (chunk << 3)]);
#pragma unroll
        for (int nf = 0; nf < 4; ++nf)
          acc[mf][nf] = __builtin_amdgcn_mfma_f32_16x16x32_bf16(af, bf[nf][ks], acc[mf][nf], 0, 0, 0);
      }
    if (kt < KT - 1) cvt_store(cur ^ 1, n0, n1);
    __syncthreads();
  }

  // epilogue: relu, dot with W_att slice, reduce 16 lanes -> row partial
  float w[4];
#pragma unroll
  for (int nf = 0; nf < 4; ++nf) w[nf] = Watt[wid * 64 + nf * 16 + lr];
#pragma unroll
  for (int mf = 0; mf < 4; ++mf)
#pragma unroll
    for (int r = 0; r < 4; ++r) {
      float s = 0.f;
#pragma unroll
      for (int nf = 0; nf < 4; ++nf) s = fmaf(fmaxf(acc[mf][nf][r], 0.f), w[nf], s);
      s += __shfl_xor(s, 1);
      s += __shfl_xor(s, 2);
      s += __shfl_xor(s, 4);
      s += __shfl_xor(s, 8);
      if (lr == 0) att_w[wid][mf * 16 + lq * 4 + r] = s;
    }
  __syncthreads();
  if (tid < BM) {
    float s = 0.f;
#pragma unroll
    for (int wv = 0; wv < 8; ++wv) s += att_w[wv][tid];
    att[row0 + tid] = s + batt[0];
  }
}

// ---------------- kernel 3: row softmax over L (in-place on att buffer)
__global__ void k_softmax(float* __restrict__ alpha) {
  int b = blockIdx.x, lane = threadIdx.x;  // 64 threads
  float* ar = alpha + (size_t)b * NL;
  float v[4];
#pragma unroll
  for (int i = 0; i < 4; ++i) {
    int l = i * 64 + lane;
    v[i] = (l < NL) ? ar[l] : -1e30f;
  }
  float m = fmaxf(fmaxf(v[0], v[1]), fmaxf(v[2], v[3]));
#pragma unroll
  for (int o = 32; o >= 1; o >>= 1) m = fmaxf(m, __shfl_xor(m, o));
  float e[4];
  float s = 0.f;
#pragma unroll
  for (int i = 0; i < 4; ++i) {
    int l = i * 64 + lane;
    e[i] = (l < NL) ? __expf(v[i] - m) : 0.f;
    s += e[i];
  }
#pragma unroll
  for (int o = 32; o >= 1; o >>= 1) s += __shfl_xor(s, o);
  float inv = 1.f / s;
#pragma unroll
  for (int i = 0; i < 4; ++i) {
    int l = i * 64 + lane;
    if (l < NL) ar[l] = e[i] * inv;
  }
}

// ---------------- kernel 4: awe[b][e] = sum_l alpha[b][l] * enc[b][l][e]
__global__ void k_awe(const float* __restrict__ enc, const float* __restrict__ alpha,
                      float* __restrict__ awe) {
  __shared__ float al[NL];
  int b = blockIdx.y, ch = blockIdx.x, tid = threadIdx.x;  // 256 threads, ch 0..1
  if (tid < NL) al[tid] = alpha[(size_t)b * NL + tid];
  __syncthreads();
  int e0 = ch * 1024 + tid * 4;
  const float* ep = enc + (size_t)b * NL * NE + e0;
  f32x4 s = {0.f, 0.f, 0.f, 0.f};
#pragma unroll 4
  for (int l = 0; l < NL; ++l) {
    f32x4 v = *reinterpret_cast<const f32x4*>(ep + (size_t)l * NE);
    float a = al[l];
    s[0] = fmaf(a, v[0], s[0]);
    s[1] = fmaf(a, v[1], s[1]);
    s[2] = fmaf(a, v[2], s[2]);
    s[3] = fmaf(a, v[3], s[3]);
  }
  *reinterpret_cast<f32x4*>(awe + (size_t)b * NE + e0) = s;
}

extern "C" void kernel_launch(void* const* d_in, const int* in_sizes, int n_in,
                              void* d_out, int out_size, void* d_ws, size_t ws_size,
                              hipStream_t stream) {
  const float* enc  = (const float*)d_in[0];
  const float* dec  = (const float*)d_in[1];
  const float* Wenc = (const float*)d_in[2];
  const float* benc = (const float*)d_in[3];
  const float* Wdec = (const float*)d_in[4];
  const float* bdec = (const float*)d_in[5];
  const float* Watt = (const float*)d_in[6];
  const float* batt = (const float*)d_in[7];

  float* awe   = (float*)d_out;                     // [NB][NE]
  float* alpha = (float*)d_out + (size_t)NB * NE;   // [NB][NL] (att written here, softmaxed in place)

  char* ws = (char*)d_ws;
  unsigned short* Bp = (unsigned short*)ws;                       // 2 MB
  float* d2 = (float*)(ws + (size_t)2 * 1024 * 1024);             // 512 KB

  k_pack_b<<<dim3(512), dim3(256), 0, stream>>>(Wenc, Bp);
  k_dec<<<dim3(NB), dim3(512), 0, stream>>>(dec, Wdec, bdec, benc, d2);
  k_main<<<dim3(NM / BM), dim3(512), 0, stream>>>(enc, Bp, d2, Watt, batt, alpha);
  k_softmax<<<dim3(NB), dim3(64), 0, stream>>>(alpha);
  k_awe<<<dim3(2, NB), dim3(256), 0, stream>>>(enc, alpha, awe);
}

// Round 2
// 256.825 us; speedup vs baseline: 1.0298x; 1.0298x over previous
//
#include <hip/hip_runtime.h>
#include <hip/hip_bf16.h>
#include <stdint.h>

// Problem dims
#define NB 256
#define NL 196
#define NE 2048
#define ND 512
#define NA 512
#define NM (NB * NL)  // 50176

typedef __attribute__((ext_vector_type(4))) float f32x4;
typedef __attribute__((ext_vector_type(8))) short bf16x8;

// Native scalar cast — compiler lowers to HW bf16 cvt (v_cvt_pk_bf16_f32 pairs).
static __device__ __forceinline__ unsigned short f2bf(float f) {
  __hip_bfloat16 h = __float2bfloat16(f);
  unsigned short u;
  __builtin_memcpy(&u, &h, 2);
  return u;
}

// ---------------- kernel 0: prep = pack W_enc (blocks 0..255) + decoder GEMV (blocks 256..511)
// Bpack[ntile(32)][kt32(64)][lane(64)][j(8)] = W_enc[kt32*32 + (lane>>4)*8 + j][ntile*16 + (lane&15)]
__global__ __launch_bounds__(512) void k_prep(
    const float* __restrict__ W, unsigned short* __restrict__ Bp,
    const float* __restrict__ dec, const float* __restrict__ Wd,
    const float* __restrict__ bd, const float* __restrict__ be,
    float* __restrict__ d2) {
  if (blockIdx.x < 256) {
    int t = blockIdx.x * 512 + threadIdx.x;  // 0..131071
    int lane = t & 63;
    int kt32 = (t >> 6) & 63;
    int ntile = t >> 12;  // 0..31
    int col = ntile * 16 + (lane & 15);
    int k0 = kt32 * 32 + ((lane >> 4) << 3);
    bf16x8 o;
#pragma unroll
    for (int j = 0; j < 8; ++j) o[j] = (short)f2bf(W[(size_t)(k0 + j) * NA + col]);
    *reinterpret_cast<bf16x8*>(Bp + ((size_t)t << 3)) = o;
  } else {
    __shared__ float dh[ND];
    int b = blockIdx.x - 256, tid = threadIdx.x;  // 512 threads
    dh[tid] = dec[(size_t)b * ND + tid];
    __syncthreads();
    float s = bd[tid] + be[tid];
#pragma unroll 8
    for (int e = 0; e < ND; ++e) s = fmaf(dh[e], Wd[(size_t)e * NA + tid], s);
    d2[(size_t)b * NA + tid] = s;
  }
}

// ---------------- kernel 1: main fused GEMM + relu-dot epilogue
// att[row] = sum_a relu( (enc@W_enc)[row][a] + d2[b(row)][a] ) * W_att[a] + b_att
#define BM 64
#define BK 64
#define KT (NE / BK)  // 32

__global__ __launch_bounds__(512, 4) void k_main(
    const float* __restrict__ A,            // [NM][NE] fp32
    const unsigned short* __restrict__ Bp,  // packed bf16 B
    const float* __restrict__ d2,           // [NB][NA]
    const float* __restrict__ Watt,         // [NA]
    const float* __restrict__ batt,         // [1]
    float* __restrict__ att)                // [NM]
{
  __shared__ unsigned short As[2][BM * BK];  // 8 KB each, XOR-swizzled rows
  __shared__ float att_w[8][BM];

  const int tid = threadIdx.x;
  const int lane = tid & 63;
  const int wid = tid >> 6;   // wave 0..7 -> col slice wid*64
  const int lq = lane >> 4;   // 0..3
  const int lr = lane & 15;
  const int row0 = blockIdx.x * BM;

  // acc init with d2 (folds decoder term + both biases into MFMA C-in)
  f32x4 acc[4][4];
#pragma unroll
  for (int mf = 0; mf < 4; ++mf)
#pragma unroll
    for (int r = 0; r < 4; ++r) {
      int rowg = row0 + mf * 16 + lq * 4 + r;
      int bb = rowg / NL;
      const float* d2r = d2 + (size_t)bb * NA + wid * 64 + lr;
#pragma unroll
      for (int nf = 0; nf < 4; ++nf) acc[mf][nf][r] = d2r[nf * 16];
    }

  // A staging map: thread -> (row 0..63, 8-elem k-chunk 0..7)
  const int srow = tid >> 3;
  const int skc = tid & 7;
  const float* ag = A + (size_t)(row0 + srow) * NE + skc * 8;
  const int swz_w = srow * 64 + ((skc ^ (srow & 7)) << 3);  // ushort index, 16B-swizzled

  auto cvt_store = [&](int buf, const f32x4& a, const f32x4& b) {
    bf16x8 o;
    o[0] = (short)f2bf(a[0]); o[1] = (short)f2bf(a[1]);
    o[2] = (short)f2bf(a[2]); o[3] = (short)f2bf(a[3]);
    o[4] = (short)f2bf(b[0]); o[5] = (short)f2bf(b[1]);
    o[6] = (short)f2bf(b[2]); o[7] = (short)f2bf(b[3]);
    *reinterpret_cast<bf16x8*>(&As[buf][swz_w]) = o;
  };

  // prologue: stage kt=0
  {
    f32x4 p0 = *reinterpret_cast<const f32x4*>(ag);
    f32x4 p1 = *reinterpret_cast<const f32x4*>(ag + 4);
    cvt_store(0, p0, p1);
  }
  __syncthreads();

  // per-wave B base: element ((ntile*64 + kt32)*64 + lane)*8, ntile = wid*4+nf
  const unsigned short* bpw = Bp + (size_t)(wid * 4) * 32768 + lane * 8;

  for (int kt = 0; kt < KT; ++kt) {
    const int cur = kt & 1;
    f32x4 n0, n1;
    if (kt < KT - 1) {
      const float* agn = ag + (size_t)(kt + 1) * BK;
      n0 = *reinterpret_cast<const f32x4*>(agn);
      n1 = *reinterpret_cast<const f32x4*>(agn + 4);
    }
    // B fragments for this K-tile (L2-resident, coalesced 1KB/wave each)
    bf16x8 bf[4][2];
#pragma unroll
    for (int nf = 0; nf < 4; ++nf)
#pragma unroll
      for (int ks = 0; ks < 2; ++ks)
        bf[nf][ks] = *reinterpret_cast<const bf16x8*>(bpw + (size_t)nf * 32768 + (kt * 2 + ks) * 512);
    // A fragments from LDS + MFMA
#pragma unroll
    for (int ks = 0; ks < 2; ++ks)
#pragma unroll
      for (int mf = 0; mf < 4; ++mf) {
        const int rrow = mf * 16 + lr;
        const int chunk = (ks * 4 + lq) ^ (lr & 7);
        bf16x8 af = *reinterpret_cast<const bf16x8*>(&As[cur][rrow * 64 + (chunk << 3)]);
#pragma unroll
        for (int nf = 0; nf < 4; ++nf)
          acc[mf][nf] = __builtin_amdgcn_mfma_f32_16x16x32_bf16(af, bf[nf][ks], acc[mf][nf], 0, 0, 0);
      }
    if (kt < KT - 1) cvt_store(cur ^ 1, n0, n1);
    __syncthreads();
  }

  // epilogue: relu, dot with W_att slice, reduce 16 lanes -> row partial
  float w[4];
#pragma unroll
  for (int nf = 0; nf < 4; ++nf) w[nf] = Watt[wid * 64 + nf * 16 + lr];
#pragma unroll
  for (int mf = 0; mf < 4; ++mf)
#pragma unroll
    for (int r = 0; r < 4; ++r) {
      float s = 0.f;
#pragma unroll
      for (int nf = 0; nf < 4; ++nf) s = fmaf(fmaxf(acc[mf][nf][r], 0.f), w[nf], s);
      s += __shfl_xor(s, 1);
      s += __shfl_xor(s, 2);
      s += __shfl_xor(s, 4);
      s += __shfl_xor(s, 8);
      if (lr == 0) att_w[wid][mf * 16 + lq * 4 + r] = s;
    }
  __syncthreads();
  if (tid < BM) {
    float s = 0.f;
#pragma unroll
    for (int wv = 0; wv < 8; ++wv) s += att_w[wv][tid];
    att[row0 + tid] = s + batt[0];
  }
}

// ---------------- kernel 2: fused softmax + weighted sum
// alpha[b] = softmax(att[b]); awe[b][e] = sum_l alpha[b][l] * enc[b][l][e]
__global__ __launch_bounds__(512) void k_awe(
    const float* __restrict__ enc, const float* __restrict__ att,
    float* __restrict__ alpha_out, float* __restrict__ awe) {
  __shared__ float al[256];
  const int b = blockIdx.x, tid = threadIdx.x;

  if (tid < 64) {  // wave 0: softmax over L=196
    const int lane = tid;
    const float* ar = att + (size_t)b * NL;
    float v[4];
#pragma unroll
    for (int i = 0; i < 4; ++i) {
      int l = i * 64 + lane;
      v[i] = (l < NL) ? ar[l] : -1e30f;
    }
    float m = fmaxf(fmaxf(v[0], v[1]), fmaxf(v[2], v[3]));
#pragma unroll
    for (int o = 32; o >= 1; o >>= 1) m = fmaxf(m, __shfl_xor(m, o));
    float e[4];
    float s = 0.f;
#pragma unroll
    for (int i = 0; i < 4; ++i) {
      int l = i * 64 + lane;
      e[i] = (l < NL) ? __expf(v[i] - m) : 0.f;
      s += e[i];
    }
#pragma unroll
    for (int o = 32; o >= 1; o >>= 1) s += __shfl_xor(s, o);
    float inv = 1.f / s;
#pragma unroll
    for (int i = 0; i < 4; ++i) {
      int l = i * 64 + lane;
      if (l < NL) {
        float a = e[i] * inv;
        al[l] = a;
        alpha_out[(size_t)b * NL + l] = a;
      }
    }
  }
  __syncthreads();

  // weighted sum: each thread owns 4 consecutive e; 4 independent accumulator sets
  const float* ep = enc + (size_t)b * NL * NE + tid * 4;
  f32x4 a0 = {0.f, 0.f, 0.f, 0.f}, a1 = a0, a2 = a0, a3 = a0;
#pragma unroll 2
  for (int l = 0; l < NL; l += 4) {  // NL = 196 = 4*49
    f32x4 v0 = *reinterpret_cast<const f32x4*>(ep + (size_t)l * NE);
    f32x4 v1 = *reinterpret_cast<const f32x4*>(ep + (size_t)(l + 1) * NE);
    f32x4 v2 = *reinterpret_cast<const f32x4*>(ep + (size_t)(l + 2) * NE);
    f32x4 v3 = *reinterpret_cast<const f32x4*>(ep + (size_t)(l + 3) * NE);
    float c0 = al[l], c1 = al[l + 1], c2 = al[l + 2], c3 = al[l + 3];
#pragma unroll
    for (int j = 0; j < 4; ++j) {
      a0[j] = fmaf(c0, v0[j], a0[j]);
      a1[j] = fmaf(c1, v1[j], a1[j]);
      a2[j] = fmaf(c2, v2[j], a2[j]);
      a3[j] = fmaf(c3, v3[j], a3[j]);
    }
  }
  f32x4 s4;
#pragma unroll
  for (int j = 0; j < 4; ++j) s4[j] = (a0[j] + a1[j]) + (a2[j] + a3[j]);
  *reinterpret_cast<f32x4*>(awe + (size_t)b * NE + tid * 4) = s4;
}

extern "C" void kernel_launch(void* const* d_in, const int* in_sizes, int n_in,
                              void* d_out, int out_size, void* d_ws, size_t ws_size,
                              hipStream_t stream) {
  const float* enc  = (const float*)d_in[0];
  const float* dec  = (const float*)d_in[1];
  const float* Wenc = (const float*)d_in[2];
  const float* benc = (const float*)d_in[3];
  const float* Wdec = (const float*)d_in[4];
  const float* bdec = (const float*)d_in[5];
  const float* Watt = (const float*)d_in[6];
  const float* batt = (const float*)d_in[7];

  float* awe   = (float*)d_out;                     // [NB][NE]
  float* alpha = (float*)d_out + (size_t)NB * NE;   // [NB][NL]

  char* ws = (char*)d_ws;
  unsigned short* Bp = (unsigned short*)ws;                       // 2 MB
  float* d2  = (float*)(ws + (size_t)2 * 1024 * 1024);            // 512 KB
  float* att = (float*)(ws + (size_t)2 * 1024 * 1024 + 512 * 1024);  // 200 KB

  k_prep<<<dim3(512), dim3(512), 0, stream>>>(Wenc, Bp, dec, Wdec, bdec, benc, d2);
  k_main<<<dim3(NM / BM), dim3(512), 0, stream>>>(enc, Bp, d2, Watt, batt, att);
  k_awe<<<dim3(NB), dim3(512), 0, stream>>>(enc, att, alpha, awe);
}